// Round 1
// 4571.370 us; speedup vs baseline: 1.0288x; 1.0288x over previous
//
#include <hip/hip_runtime.h>

// Problem constants (reference: T=512, N=256, H=256, HR=64, WC=128, V=64)
#define TSTEPS 512
#define NBATCH 256
#define HID    256
#define TCHUNK 64
#define NCHUNK 8

typedef __attribute__((ext_vector_type(8))) short bf16x8;
typedef __attribute__((ext_vector_type(4))) float f32x4;

__device__ __forceinline__ unsigned short f2b(float x) {
    union { float f; unsigned int u; } c; c.f = x;
    unsigned int u = c.u;
    return (unsigned short)((u + 0x7fffu + ((u >> 16) & 1u)) >> 16);
}
__device__ __forceinline__ float sigmoidf_(float x) { return 1.f / (1.f + __expf(-x)); }
__device__ __forceinline__ float tanhf_(float x)    { return 1.f - 2.f / (1.f + __expf(2.f * x)); }

__device__ __forceinline__ void gload_lds16(const float* g, float* l) {
    __builtin_amdgcn_global_load_lds(
        (const __attribute__((address_space(1))) unsigned int*)g,
        (__attribute__((address_space(3))) unsigned int*)l,
        16, 0, 0);
}

// ---------------------------------------------------------------------------
// Generic GEMM: C[M,N] = act(A[M,K] @ B + bias), bf16 MFMA, fp32 in/out.
// (unchanged — verified correct)
// ---------------------------------------------------------------------------
template<bool TRANS_B, int ACT>
__global__ __launch_bounds__(256) void gemm_f32(
    const float* __restrict__ A, long lda, long sA,
    const float* __restrict__ B, long ldb, long sB,
    const float* __restrict__ bias,
    float* __restrict__ C, long ldc, long sC,
    int M, int N, int K)
{
    __shared__ __align__(16) unsigned short As[64][32];  // [m][k] bf16
    __shared__ __align__(16) unsigned short Bs[64][32];  // [n][k] bf16
    const int z = blockIdx.z;
    A += (long)z * sA; B += (long)z * sB; C += (long)z * sC;
    const int n0 = blockIdx.x * 64, m0 = blockIdx.y * 64;
    const int tid  = threadIdx.x;
    const int lane = tid & 63, w = tid >> 6;
    const int wr = (w >> 1) * 32, wc = (w & 1) * 32;

    f32x4 acc[2][2];
#pragma unroll
    for (int i = 0; i < 2; i++)
#pragma unroll
        for (int j = 0; j < 2; j++) acc[i][j] = (f32x4){0.f, 0.f, 0.f, 0.f};

    for (int k0 = 0; k0 < K; k0 += 32) {
        {   // stage A tile: 64 rows x 32 k
            const int r = tid >> 2, ck = (tid & 3) << 3;
            const float* s = A + (long)(m0 + r) * lda + k0 + ck;
            float4 v0 = *(const float4*)s, v1 = *(const float4*)(s + 4);
            unsigned short* d = &As[r][ck];
            d[0] = f2b(v0.x); d[1] = f2b(v0.y); d[2] = f2b(v0.z); d[3] = f2b(v0.w);
            d[4] = f2b(v1.x); d[5] = f2b(v1.y); d[6] = f2b(v1.z); d[7] = f2b(v1.w);
        }
        if (TRANS_B) {  // B stored (N,K)
            const int r = tid >> 2, ck = (tid & 3) << 3;
            const float* s = B + (long)(n0 + r) * ldb + k0 + ck;
            float4 v0 = *(const float4*)s, v1 = *(const float4*)(s + 4);
            unsigned short* d = &Bs[r][ck];
            d[0] = f2b(v0.x); d[1] = f2b(v0.y); d[2] = f2b(v0.z); d[3] = f2b(v0.w);
            d[4] = f2b(v1.x); d[5] = f2b(v1.y); d[6] = f2b(v1.z); d[7] = f2b(v1.w);
        } else {        // B stored (K,N): scatter-transpose
            const int kk = tid >> 3, cn = (tid & 7) << 3;
            const float* s = B + (long)(k0 + kk) * ldb + n0 + cn;
            float4 v0 = *(const float4*)s, v1 = *(const float4*)(s + 4);
            Bs[cn + 0][kk] = f2b(v0.x); Bs[cn + 1][kk] = f2b(v0.y);
            Bs[cn + 2][kk] = f2b(v0.z); Bs[cn + 3][kk] = f2b(v0.w);
            Bs[cn + 4][kk] = f2b(v1.x); Bs[cn + 5][kk] = f2b(v1.y);
            Bs[cn + 6][kk] = f2b(v1.z); Bs[cn + 7][kk] = f2b(v1.w);
        }
        __syncthreads();
        const int q8 = (lane >> 4) << 3;
        bf16x8 a0 = *(const bf16x8*)&As[wr +      (lane & 15)][q8];
        bf16x8 a1 = *(const bf16x8*)&As[wr + 16 + (lane & 15)][q8];
        bf16x8 b0 = *(const bf16x8*)&Bs[wc +      (lane & 15)][q8];
        bf16x8 b1 = *(const bf16x8*)&Bs[wc + 16 + (lane & 15)][q8];
        acc[0][0] = __builtin_amdgcn_mfma_f32_16x16x32_bf16(a0, b0, acc[0][0], 0, 0, 0);
        acc[0][1] = __builtin_amdgcn_mfma_f32_16x16x32_bf16(a0, b1, acc[0][1], 0, 0, 0);
        acc[1][0] = __builtin_amdgcn_mfma_f32_16x16x32_bf16(a1, b0, acc[1][0], 0, 0, 0);
        acc[1][1] = __builtin_amdgcn_mfma_f32_16x16x32_bf16(a1, b1, acc[1][1], 0, 0, 0);
        __syncthreads();
    }
    const int cq = lane >> 4, cc = lane & 15;
#pragma unroll
    for (int i = 0; i < 2; i++)
#pragma unroll
        for (int j = 0; j < 2; j++) {
#pragma unroll
            for (int rg = 0; rg < 4; rg++) {
                int row = m0 + wr + i * 16 + cq * 4 + rg;
                int col = n0 + wc + j * 16 + cc;
                float v = acc[i][j][rg];
                if (bias) v += bias[col];
                if (ACT == 1) v = v > 0.f ? v : 0.f;
                C[(long)row * ldc + col] = v;
            }
        }
}

// ---------------------------------------------------------------------------
// Helpers
// ---------------------------------------------------------------------------
__global__ void transpose_768(const float* __restrict__ src, float* __restrict__ dst)
{   // src (256,768) -> dst (768,256)
    int c = blockIdx.x, t = threadIdx.x;
    dst[(long)c * 256 + t] = src[(long)t * 768 + c];
}

__global__ void combine_bias(const float* a0, const float* b0,
                             const float* a1, const float* b1,
                             const float* a2, const float* b2,
                             float* o0, float* o1, float* o2)
{
    int i = blockIdx.x * 256 + threadIdx.x;   // 0..767
    o0[i] = a0[i] + b0[i];
    o1[i] = a1[i] + b1[i];
    o2[i] = a2[i] + b2[i];
}

__global__ void seq_major(const float* __restrict__ M, float* __restrict__ Mseq)
{   // M (n,s,256) -> Mseq (s,n,256)
    int b = blockIdx.x;               // s*256+n
    int s = b >> 8, n = b & 255;
    int t = threadIdx.x;
    Mseq[(long)b * 256 + t] = M[((long)n * 64 + s) * 256 + t];
}

__global__ void build_x(const float* __restrict__ values, const float* __restrict__ Mbuf,
                        const int* __restrict__ actions, const int* __restrict__ a0,
                        float* __restrict__ Xc, int t0)
{   // Xc row (tl*256+n) = [values[t,n,0:64], M[n, a_prev(t,n), 0:256]]
    int m = blockIdx.x;               // tl*256+n
    int tl = m >> 8, n = m & 255;
    int t = t0 + tl;
    int c = threadIdx.x;              // 0..319
    float v;
    if (c < 64) {
        v = values[((long)t * 256 + n) * 64 + c];
    } else {
        int ap = (t == 0) ? a0[n] : actions[(long)(t - 1) * 256 + n];
        v = Mbuf[((long)n * 64 + ap) * 256 + (c - 64)];
    }
    Xc[(long)m * 320 + c] = v;
}

// ---------------------------------------------------------------------------
// Weight-stationary MFMA GRU scan, v2.
// 16 n-rows per block, 512 threads (8 waves, 2 waves/SIMD, 256-VGPR budget).
// Wave w owns h-cols [w*32,(w+1)*32) and the matching 3x32 gate columns;
// its Whh^T slice lives in 48 bf16x8 B-frags (192 VGPR).
// Double-buffered LDS for BOTH the bf16 h staging (hbuf[2]) and the
// prefetched gate inputs (gibuf[2]) -> ONE barrier per step with a counted
// s_waitcnt vmcnt(8): only this step's 8 output stores may stay in flight
// across the barrier; the gi[s+1] prefetch (6 global_load_lds, issued at
// step start) is guaranteed complete, with a full step of latency cover.
// No vmcnt(0) drains inside the loop.
//
// vmcnt accounting per wave per step (order pinned by asm memory fences):
//   P1: 6 global_load_lds (gi[s+1])   P4: 8 global_store_dword (h(s))
//   P5: s_waitcnt vmcnt(8) -> forces P1 loads (and last step's stores)
//       retired; leaves <=8 (this step's stores) outstanding.
// ---------------------------------------------------------------------------
template<int KGRU>
__global__ __launch_bounds__(512, 2) void scan_mfma(
    const float* __restrict__ gi0, const float* __restrict__ gi1,
    const float* __restrict__ WT0, const float* __restrict__ WT1,
    const float* __restrict__ h_init,   // null-equivalent for KGRU (zeros)
    float* __restrict__ outp,           // main: Hallc ; kgru: Kbuf
    float* __restrict__ h_state,        // main only
    int steps)
{
    __shared__ __align__(16) unsigned short hbuf[2][16][264];  // bf16 h, dbuf
    __shared__ __align__(16) float gibuf[2][16 * 772];         // gate inputs, dbuf

    const int tid = threadIdx.x;
    const int w = tid >> 6, lane = tid & 63;
    const int q = lane >> 4, c = lane & 15, q8 = q << 3;
    const int n0 = blockIdx.x * 16;
    const int d = KGRU ? blockIdx.y : 0;
    const float* gi = d ? gi1 : gi0;
    const float* WT = d ? WT1 : WT0;
    const int wcol = w * 32;

    // ---- one-time: weight B-fragments (wave w -> gate cols g*256+wcol+hh*16) ----
    bf16x8 Bf[6][8];
#pragma unroll
    for (int g = 0; g < 3; g++)
#pragma unroll
        for (int hh = 0; hh < 2; hh++) {
            const float* src = WT + (long)(g * 256 + wcol + hh * 16 + c) * 256;
#pragma unroll
            for (int kt = 0; kt < 8; kt++) {
                const float* s8 = src + kt * 32 + q8;
                float4 u0 = *(const float4*)s8, u1 = *(const float4*)(s8 + 4);
                bf16x8 b;
                b[0] = (short)f2b(u0.x); b[1] = (short)f2b(u0.y);
                b[2] = (short)f2b(u0.z); b[3] = (short)f2b(u0.w);
                b[4] = (short)f2b(u1.x); b[5] = (short)f2b(u1.y);
                b[6] = (short)f2b(u1.z); b[7] = (short)f2b(u1.w);
                Bf[g * 2 + hh][kt] = b;
            }
        }

    // ---- h init: registers (C-layout) + bf16 staging into hbuf[1] ----
    f32x4 hreg[2];
#pragma unroll
    for (int hh = 0; hh < 2; hh++)
#pragma unroll
        for (int rg = 0; rg < 4; rg++) {
            float v = 0.f;
            if (!KGRU) v = h_init[(long)(n0 + q * 4 + rg) * 256 + wcol + hh * 16 + c];
            hreg[hh][rg] = v;
            hbuf[1][q * 4 + rg][wcol + hh * 16 + c] = f2b(v);
        }

    // ---- prologue: prefetch gi[0] -> gibuf[0] (48 x 1KB, 6 per wave) ----
    {
        int row0 = KGRU ? (d ? 63 : 0) : 0;
        const float* src = gi + ((long)row0 * 256 + n0) * 768;
#pragma unroll
        for (int i = 0; i < 6; i++) {
            int idx = w * 6 + i;              // 0..47
            int r = idx / 3, ch = idx % 3;    // 16 rows x 3 chunks of 256 floats
            gload_lds16(src + (long)r * 768 + ch * 256 + lane * 4,
                        &gibuf[0][r * 772 + ch * 256]);
        }
    }
    __syncthreads();   // vmcnt(0) lgkmcnt(0) drain: gi[0] + hbuf[1] visible

    for (int s = 0; s < steps; s++) {
        const int cur = s & 1;

        // ---- P1: issue gi prefetch for step s+1 into gibuf[cur^1] ----
        if (s + 1 < steps) {
            int rown = KGRU ? (d ? (63 - (s + 1)) : (s + 1)) : (s + 1);
            const float* src = gi + ((long)rown * 256 + n0) * 768;
#pragma unroll
            for (int i = 0; i < 6; i++) {
                int idx = w * 6 + i;
                int r = idx / 3, ch = idx % 3;
                gload_lds16(src + (long)r * 768 + ch * 256 + lane * 4,
                            &gibuf[cur ^ 1][r * 772 + ch * 256]);
            }
        }
        // pin: all P1 loads issue before any later vmem (exact vmcnt counting)
        asm volatile("" ::: "memory");

        // ---- P2: gh = h(s-1) @ Whh : 48 mfma/wave, weight-stationary ----
        f32x4 acc[6];
#pragma unroll
        for (int t = 0; t < 6; t++) acc[t] = (f32x4){0.f, 0.f, 0.f, 0.f};
        const unsigned short* hrd = &hbuf[cur ^ 1][0][0];
#pragma unroll
        for (int kt = 0; kt < 8; kt++) {
            bf16x8 a = *(const bf16x8*)&hrd[c * 264 + kt * 32 + q8];
#pragma unroll
            for (int t = 0; t < 6; t++)
                acc[t] = __builtin_amdgcn_mfma_f32_16x16x32_bf16(a, Bf[t][kt], acc[t], 0, 0, 0);
        }

        const int out_row = KGRU ? (d ? (63 - s) : s) : s;
        const float* gp = &gibuf[cur][0];
        unsigned short* hwr = &hbuf[cur][0][0];

        // ---- P3/P4: gates + state update + stage h(s) + output stores ----
#pragma unroll
        for (int hh = 0; hh < 2; hh++) {
            f32x4 hn;
#pragma unroll
            for (int rg = 0; rg < 4; rg++) {
                int lrow = q * 4 + rg;
                int col  = wcol + hh * 16 + c;
                float gr = gp[lrow * 772 +       col];
                float gz = gp[lrow * 772 + 256 + col];
                float gn = gp[lrow * 772 + 512 + col];
                float r  = sigmoidf_(gr + acc[0 + hh][rg]);
                float zg = sigmoidf_(gz + acc[2 + hh][rg]);
                float nn = tanhf_(gn + r * acc[4 + hh][rg]);
                hn[rg] = (1.f - zg) * nn + zg * hreg[hh][rg];
            }
            hreg[hh] = hn;
#pragma unroll
            for (int rg = 0; rg < 4; rg++) {
                int lrow = q * 4 + rg;
                int col  = wcol + hh * 16 + c;
                float v  = hn[rg];
                hwr[lrow * 264 + col] = f2b(v);
                if (KGRU)
                    outp[((long)(n0 + lrow) * 64 + out_row) * 512 + d * 256 + col] = v;
                else
                    outp[((long)s * 256 + n0 + lrow) * 256 + col] = v;
            }
        }

        // ---- P5: single counted barrier ----
        asm volatile("s_waitcnt vmcnt(8) lgkmcnt(0)" ::: "memory");
        __builtin_amdgcn_sched_barrier(0);
        __builtin_amdgcn_s_barrier();
        __builtin_amdgcn_sched_barrier(0);
    }

    if (!KGRU) {
#pragma unroll
        for (int hh = 0; hh < 2; hh++)
#pragma unroll
            for (int rg = 0; rg < 4; rg++)
                h_state[(long)(n0 + q * 4 + rg) * 256 + wcol + hh * 16 + c] = hreg[hh][rg];
    }
}

// ---------------------------------------------------------------------------
// Epilogue: per (t,n) write a, v=critic(h), h copy, softmax(logits).
// ---------------------------------------------------------------------------
__global__ __launch_bounds__(64) void epilogue_k(
    const float* __restrict__ Hallc, const float* __restrict__ Lc,
    const int* __restrict__ actions,
    const float* __restrict__ critic_W, const float* __restrict__ critic_b,
    float* __restrict__ out, int t0)
{
    int m = blockIdx.x;               // tl*256+n
    int tl = m >> 8, n = m & 255;
    int t = t0 + tl;
    int j = threadIdx.x;              // 0..63
    long o = ((long)t * 256 + n) * 322;
    const float* h = Hallc + (long)m * 256;
    float part = 0.f;
#pragma unroll
    for (int i = 0; i < 4; i++) {
        float hv = h[j + 64 * i];
        out[o + 2 + j + 64 * i] = hv;
        part += hv * critic_W[j + 64 * i];
    }
    for (int off = 32; off > 0; off >>= 1) part += __shfl_down(part, off);
    if (j == 0) {
        out[o]     = (float)actions[(long)t * 256 + n];
        out[o + 1] = part + critic_b[0];
    }
    float x = Lc[(long)m * 64 + j];
    float mx = x;
    for (int off = 32; off > 0; off >>= 1) mx = fmaxf(mx, __shfl_down(mx, off));
    mx = __shfl(mx, 0);
    float e = __expf(x - mx);
    float ssum = e;
    for (int off = 32; off > 0; off >>= 1) ssum += __shfl_down(ssum, off);
    ssum = __shfl(ssum, 0);
    out[o + 258 + j] = e / ssum;
}

// ---------------------------------------------------------------------------
extern "C" void kernel_launch(void* const* d_in, const int* in_sizes, int n_in,
                              void* d_out, int out_size, void* d_ws, size_t ws_size,
                              hipStream_t stream)
{
    const float* values   = (const float*)d_in[0];
    const float* mdp      = (const float*)d_in[1];
    const int*   actions  = (const int*)  d_in[2];
    const int*   a0       = (const int*)  d_in[3];
    const float* h0       = (const float*)d_in[4];
    const float* emb_W    = (const float*)d_in[5];
    const float* emb_b    = (const float*)d_in[6];
    const float* gfw_Wih  = (const float*)d_in[7];
    const float* gfw_Whh  = (const float*)d_in[8];
    const float* gfw_bih  = (const float*)d_in[9];
    const float* gfw_bhh  = (const float*)d_in[10];
    const float* gbw_Wih  = (const float*)d_in[11];
    const float* gbw_Whh  = (const float*)d_in[12];
    const float* gbw_bih  = (const float*)d_in[13];
    const float* gbw_bhh  = (const float*)d_in[14];
    const float* f0_W     = (const float*)d_in[15];
    const float* f0_b     = (const float*)d_in[16];
    const float* f1_W     = (const float*)d_in[17];
    const float* f1_b     = (const float*)d_in[18];
    const float* cell_Wih = (const float*)d_in[19];
    const float* cell_Whh = (const float*)d_in[20];
    const float* cell_bih = (const float*)d_in[21];
    const float* cell_bhh = (const float*)d_in[22];
    const float* critic_W = (const float*)d_in[23];
    const float* critic_b = (const float*)d_in[24];
    const float* qg_W     = (const float*)d_in[25];
    const float* qg_b     = (const float*)d_in[26];
    float* out = (float*)d_out;

    char* base = (char*)d_ws;
    size_t off = 0;
    auto alloc = [&](size_t nf) -> float* {
        float* p = (float*)(base + off);
        off += nf * sizeof(float);
        off = (off + 255) & ~(size_t)255;
        return p;
    };
    float* Mbuf   = alloc(16384ull * 256);   // (n,s,H) line embeddings
    float* Mseq   = alloc(16384ull * 256);   // (s,n,H)
    float* gfA    = alloc(16384ull * 768);   // fw gate inputs (bias folded)
    float* gbA    = alloc(16384ull * 768);   // bw gate inputs (bias folded)
    float* Kbuf   = alloc(256ull * 64 * 512);// K (n, s, 2H)
    float* WTf    = alloc(768ull * 256);
    float* WTb    = alloc(768ull * 256);
    float* WTc    = alloc(768ull * 256);
    float* hstate = alloc(256ull * 256);
    float* Xc     = alloc(16384ull * 320);
    float* X0c    = alloc(16384ull * 256);
    float* X1c    = alloc(16384ull * 256);
    float* GIc    = alloc(16384ull * 768);
    float* Qc     = alloc(16384ull * 512);
    float* Lc     = alloc(16384ull * 64);
    float* Hallc  = alloc(16384ull * 256);
    float* bias_f = alloc(768);
    float* bias_b = alloc(768);
    float* bias_c = alloc(768);
    (void)ws_size; (void)in_sizes; (void)n_in; (void)out_size;

    dim3 blk(256);

    // Phase 1: embeddings + line-GRU gate inputs + weight prep
    gemm_f32<false, 0><<<dim3(4, 256, 1), blk, 0, stream>>>(
        mdp, 128, 0, emb_W, 256, 0, emb_b, Mbuf, 256, 0, 16384, 256, 128);
    seq_major<<<dim3(16384), blk, 0, stream>>>(Mbuf, Mseq);
    transpose_768<<<dim3(768), blk, 0, stream>>>(gfw_Whh, WTf);
    transpose_768<<<dim3(768), blk, 0, stream>>>(gbw_Whh, WTb);
    transpose_768<<<dim3(768), blk, 0, stream>>>(cell_Whh, WTc);
    combine_bias<<<dim3(3), blk, 0, stream>>>(gfw_bih, gfw_bhh, gbw_bih, gbw_bhh,
                                              cell_bih, cell_bhh, bias_f, bias_b, bias_c);
    gemm_f32<false, 0><<<dim3(12, 256, 1), blk, 0, stream>>>(
        Mseq, 256, 0, gfw_Wih, 768, 0, bias_f, gfA, 768, 0, 16384, 768, 256);
    gemm_f32<false, 0><<<dim3(12, 256, 1), blk, 0, stream>>>(
        Mseq, 256, 0, gbw_Wih, 768, 0, bias_b, gbA, 768, 0, 16384, 768, 256);
    scan_mfma<1><<<dim3(16, 2, 1), dim3(512), 0, stream>>>(
        gfA, gbA, WTf, WTb, nullptr, Kbuf, nullptr, 64);

    // Phase 2/3: chunked x-path GEMMs -> scan -> query/logits/epilogue
    for (int c = 0; c < NCHUNK; c++) {
        int t0 = c * TCHUNK;
        build_x<<<dim3(16384), dim3(320), 0, stream>>>(values, Mbuf, actions, a0, Xc, t0);
        gemm_f32<false, 1><<<dim3(4, 256, 1), blk, 0, stream>>>(
            Xc, 320, 0, f0_W, 256, 0, f0_b, X0c, 256, 0, 16384, 256, 320);
        gemm_f32<false, 1><<<dim3(4, 256, 1), blk, 0, stream>>>(
            X0c, 256, 0, f1_W, 256, 0, f1_b, X1c, 256, 0, 16384, 256, 256);
        gemm_f32<false, 0><<<dim3(12, 256, 1), blk, 0, stream>>>(
            X1c, 256, 0, cell_Wih, 768, 0, bias_c, GIc, 768, 0, 16384, 768, 256);
        scan_mfma<0><<<dim3(16, 1, 1), dim3(512), 0, stream>>>(
            GIc, nullptr, WTc, nullptr, (c == 0) ? h0 : (const float*)hstate,
            Hallc, hstate, TCHUNK);
        gemm_f32<false, 0><<<dim3(8, 256, 1), blk, 0, stream>>>(
            Hallc, 256, 0, qg_W, 512, 0, qg_b, Qc, 512, 0, 16384, 512, 256);
        gemm_f32<true, 0><<<dim3(1, 1, 256), blk, 0, stream>>>(
            Qc, 131072, 512, Kbuf, 512, 32768, nullptr, Lc, 16384, 64, 64, 64, 512);
        epilogue_k<<<dim3(16384), dim3(64), 0, stream>>>(
            Hallc, Lc, actions, critic_W, critic_b, out, t0);
    }
}

// Round 3
// 2757.921 us; speedup vs baseline: 1.7052x; 1.6575x over previous
//
#include <hip/hip_runtime.h>

// Problem constants (reference: T=512, N=256, H=256, HR=64, WC=128, V=64)
#define TSTEPS 512
#define NBATCH 256
#define HID    256
#define TCHUNK 64
#define NCHUNK 8

typedef __attribute__((ext_vector_type(8))) short bf16x8;
typedef __attribute__((ext_vector_type(4))) float f32x4;

__device__ __forceinline__ unsigned short f2b(float x) {
    union { float f; unsigned int u; } c; c.f = x;
    unsigned int u = c.u;
    return (unsigned short)((u + 0x7fffu + ((u >> 16) & 1u)) >> 16);
}

__device__ __forceinline__ void gload_lds16(const float* g, float* l) {
    __builtin_amdgcn_global_load_lds(
        (const __attribute__((address_space(1))) unsigned int*)g,
        (__attribute__((address_space(3))) unsigned int*)l,
        16, 0, 0);
}

// ---------------------------------------------------------------------------
// Generic GEMM: C[M,N] = act(A[M,K] @ B + bias), bf16 MFMA, fp32 in/out.
// (unchanged — verified correct)
// ---------------------------------------------------------------------------
template<bool TRANS_B, int ACT>
__global__ __launch_bounds__(256) void gemm_f32(
    const float* __restrict__ A, long lda, long sA,
    const float* __restrict__ B, long ldb, long sB,
    const float* __restrict__ bias,
    float* __restrict__ C, long ldc, long sC,
    int M, int N, int K)
{
    __shared__ __align__(16) unsigned short As[64][32];  // [m][k] bf16
    __shared__ __align__(16) unsigned short Bs[64][32];  // [n][k] bf16
    const int z = blockIdx.z;
    A += (long)z * sA; B += (long)z * sB; C += (long)z * sC;
    const int n0 = blockIdx.x * 64, m0 = blockIdx.y * 64;
    const int tid  = threadIdx.x;
    const int lane = tid & 63, w = tid >> 6;
    const int wr = (w >> 1) * 32, wc = (w & 1) * 32;

    f32x4 acc[2][2];
#pragma unroll
    for (int i = 0; i < 2; i++)
#pragma unroll
        for (int j = 0; j < 2; j++) acc[i][j] = (f32x4){0.f, 0.f, 0.f, 0.f};

    for (int k0 = 0; k0 < K; k0 += 32) {
        {   // stage A tile: 64 rows x 32 k
            const int r = tid >> 2, ck = (tid & 3) << 3;
            const float* s = A + (long)(m0 + r) * lda + k0 + ck;
            float4 v0 = *(const float4*)s, v1 = *(const float4*)(s + 4);
            unsigned short* d = &As[r][ck];
            d[0] = f2b(v0.x); d[1] = f2b(v0.y); d[2] = f2b(v0.z); d[3] = f2b(v0.w);
            d[4] = f2b(v1.x); d[5] = f2b(v1.y); d[6] = f2b(v1.z); d[7] = f2b(v1.w);
        }
        if (TRANS_B) {  // B stored (N,K)
            const int r = tid >> 2, ck = (tid & 3) << 3;
            const float* s = B + (long)(n0 + r) * ldb + k0 + ck;
            float4 v0 = *(const float4*)s, v1 = *(const float4*)(s + 4);
            unsigned short* d = &Bs[r][ck];
            d[0] = f2b(v0.x); d[1] = f2b(v0.y); d[2] = f2b(v0.z); d[3] = f2b(v0.w);
            d[4] = f2b(v1.x); d[5] = f2b(v1.y); d[6] = f2b(v1.z); d[7] = f2b(v1.w);
        } else {        // B stored (K,N): scatter-transpose
            const int kk = tid >> 3, cn = (tid & 7) << 3;
            const float* s = B + (long)(k0 + kk) * ldb + n0 + cn;
            float4 v0 = *(const float4*)s, v1 = *(const float4*)(s + 4);
            Bs[cn + 0][kk] = f2b(v0.x); Bs[cn + 1][kk] = f2b(v0.y);
            Bs[cn + 2][kk] = f2b(v0.z); Bs[cn + 3][kk] = f2b(v0.w);
            Bs[cn + 4][kk] = f2b(v1.x); Bs[cn + 5][kk] = f2b(v1.y);
            Bs[cn + 6][kk] = f2b(v1.z); Bs[cn + 7][kk] = f2b(v1.w);
        }
        __syncthreads();
        const int q8 = (lane >> 4) << 3;
        bf16x8 a0 = *(const bf16x8*)&As[wr +      (lane & 15)][q8];
        bf16x8 a1 = *(const bf16x8*)&As[wr + 16 + (lane & 15)][q8];
        bf16x8 b0 = *(const bf16x8*)&Bs[wc +      (lane & 15)][q8];
        bf16x8 b1 = *(const bf16x8*)&Bs[wc + 16 + (lane & 15)][q8];
        acc[0][0] = __builtin_amdgcn_mfma_f32_16x16x32_bf16(a0, b0, acc[0][0], 0, 0, 0);
        acc[0][1] = __builtin_amdgcn_mfma_f32_16x16x32_bf16(a0, b1, acc[0][1], 0, 0, 0);
        acc[1][0] = __builtin_amdgcn_mfma_f32_16x16x32_bf16(a1, b0, acc[1][0], 0, 0, 0);
        acc[1][1] = __builtin_amdgcn_mfma_f32_16x16x32_bf16(a1, b1, acc[1][1], 0, 0, 0);
        __syncthreads();
    }
    const int cq = lane >> 4, cc = lane & 15;
#pragma unroll
    for (int i = 0; i < 2; i++)
#pragma unroll
        for (int j = 0; j < 2; j++) {
#pragma unroll
            for (int rg = 0; rg < 4; rg++) {
                int row = m0 + wr + i * 16 + cq * 4 + rg;
                int col = n0 + wc + j * 16 + cc;
                float v = acc[i][j][rg];
                if (bias) v += bias[col];
                if (ACT == 1) v = v > 0.f ? v : 0.f;
                C[(long)row * ldc + col] = v;
            }
        }
}

// ---------------------------------------------------------------------------
// Helpers
// ---------------------------------------------------------------------------
__global__ void combine_bias(const float* a0, const float* b0,
                             const float* a1, const float* b1,
                             const float* a2, const float* b2,
                             float* o0, float* o1, float* o2)
{
    int i = blockIdx.x * 256 + threadIdx.x;   // 0..767
    o0[i] = a0[i] + b0[i];
    o1[i] = a1[i] + b1[i];
    o2[i] = a2[i] + b2[i];
}

__global__ void seq_major(const float* __restrict__ M, float* __restrict__ Mseq)
{   // M (n,s,256) -> Mseq (s,n,256)
    int b = blockIdx.x;               // s*256+n
    int s = b >> 8, n = b & 255;
    int t = threadIdx.x;
    Mseq[(long)b * 256 + t] = M[((long)n * 64 + s) * 256 + t];
}

// ---------------------------------------------------------------------------
// pack_w: pre-pack Whh (256,768) into the exact per-wave MFMA B-fragment
// layout the scan consumes, in bf16. Chunk index:
//   chunk = ((w*6 + f)*8 + kt)*64 + lane,  f = g*2+hh, lane = q*16+c
//   PK[chunk][j] = bf16( Whh[(kt*32 + q*8 + j) * 768 + g*256 + w*32 + hh*16 + c] )
// One 16B store per thread; scan loads Bf[f][kt] = PK[...] fully coalesced.
// Total per matrix: 24576 chunks * 16B = 384 KB.
// ---------------------------------------------------------------------------
__global__ __launch_bounds__(256) void pack_w(
    const float* __restrict__ Wf, const float* __restrict__ Wb, const float* __restrict__ Wc,
    unsigned short* __restrict__ Pf, unsigned short* __restrict__ Pb, unsigned short* __restrict__ Pc)
{
    int chunk = blockIdx.x * 256 + threadIdx.x;      // 0..24575
    const float* W = (blockIdx.y == 0) ? Wf : ((blockIdx.y == 1) ? Wb : Wc);
    unsigned short* P = (blockIdx.y == 0) ? Pf : ((blockIdx.y == 1) ? Pb : Pc);
    int lane = chunk & 63;
    int kt   = (chunk >> 6) & 7;
    int f    = (chunk >> 9) % 6;
    int w    = chunk / 3072;
    int g = f >> 1, hh = f & 1;
    int c = lane & 15, q = lane >> 4;
    int col = g * 256 + w * 32 + hh * 16 + c;
    int k0  = kt * 32 + q * 8;
    unsigned int v[8];
#pragma unroll
    for (int j = 0; j < 8; j++) v[j] = f2b(W[(long)(k0 + j) * 768 + col]);
    uint4 o;
    o.x = v[0] | (v[1] << 16); o.y = v[2] | (v[3] << 16);
    o.z = v[4] | (v[5] << 16); o.w = v[6] | (v[7] << 16);
    *(uint4*)&P[(long)chunk * 8] = o;
}

__global__ void build_x(const float* __restrict__ values, const float* __restrict__ Mbuf,
                        const int* __restrict__ actions, const int* __restrict__ a0,
                        float* __restrict__ Xc, int t0)
{   // Xc row (tl*256+n) = [values[t,n,0:64], M[n, a_prev(t,n), 0:256]]
    int m = blockIdx.x;               // tl*256+n
    int tl = m >> 8, n = m & 255;
    int t = t0 + tl;
    int c = threadIdx.x;              // 0..319
    float v;
    if (c < 64) {
        v = values[((long)t * 256 + n) * 64 + c];
    } else {
        int ap = (t == 0) ? a0[n] : actions[(long)(t - 1) * 256 + n];
        v = Mbuf[((long)n * 64 + ap) * 256 + (c - 64)];
    }
    Xc[(long)m * 320 + c] = v;
}

// ---------------------------------------------------------------------------
// Weight-stationary MFMA GRU scan, v3 (v3.1: fixed PK buffer sizing).
// 16 n-rows per block, 512 threads (8 waves, 2 waves/SIMD => 256 unified
// VGPR budget/wave, hard cap from block residency).
// Register budget engineering (the v1/v2 failure was fragment spill):
//   Bf (weights, pre-packed bf16)           192 regs
//   acc (3 gates x f32x4, ONE hh at a time)  12 regs   <- split-hh
//   hreg (fp32 h, 2 x f32x4)                  8 regs
//   temps/addressing                        ~35 regs
//   total ~247 <= 256  => no spill by construction.
// Whh fragments load directly from pack_w output: 48 coalesced 16B loads,
// no float->bf16 conversion in-kernel (kills the prologue pressure spike).
// Gate math uses v_rcp_f32 instead of IEEE division.
// Single barrier per step with counted s_waitcnt vmcnt(8) (6 gi prefetch
// loads forced complete, 8 output stores allowed to stay in flight).
// ---------------------------------------------------------------------------
template<int KGRU>
__global__ __launch_bounds__(512, 2) void scan_mfma(
    const float* __restrict__ gi0, const float* __restrict__ gi1,
    const unsigned short* __restrict__ PK0, const unsigned short* __restrict__ PK1,
    const float* __restrict__ h_init,   // null-equivalent for KGRU (zeros)
    float* __restrict__ outp,           // main: Hallc ; kgru: Kbuf
    float* __restrict__ h_state,        // main only
    int steps)
{
    __shared__ __align__(16) unsigned short hbuf[2][16][264];  // bf16 h, dbuf
    __shared__ __align__(16) float gibuf[2][16 * 772];         // gate inputs, dbuf

    const int tid = threadIdx.x;
    const int w = tid >> 6, lane = tid & 63;
    const int q = lane >> 4, c = lane & 15, q8 = q << 3;
    const int n0 = blockIdx.x * 16;
    const int d = KGRU ? blockIdx.y : 0;
    const float* gi = d ? gi1 : gi0;
    const unsigned short* PK = d ? PK1 : PK0;
    const int wcol = w * 32;

    // ---- one-time: weight B-fragments, straight 16B coalesced loads ----
    bf16x8 Bf[6][8];
#pragma unroll
    for (int f = 0; f < 6; f++)
#pragma unroll
        for (int kt = 0; kt < 8; kt++)
            Bf[f][kt] = *(const bf16x8*)&PK[(((long)(w * 6 + f) * 8 + kt) * 64 + lane) * 8];

    // ---- h init: registers (C-layout) + bf16 staging into hbuf[1] ----
    f32x4 hreg[2];
#pragma unroll
    for (int hh = 0; hh < 2; hh++)
#pragma unroll
        for (int rg = 0; rg < 4; rg++) {
            float v = 0.f;
            if (!KGRU) v = h_init[(long)(n0 + q * 4 + rg) * 256 + wcol + hh * 16 + c];
            hreg[hh][rg] = v;
            hbuf[1][q * 4 + rg][wcol + hh * 16 + c] = f2b(v);
        }

    // ---- prologue: prefetch gi[0] -> gibuf[0] (48 x 1KB, 6 per wave) ----
    {
        int row0 = KGRU ? (d ? 63 : 0) : 0;
        const float* src = gi + ((long)row0 * 256 + n0) * 768;
#pragma unroll
        for (int i = 0; i < 6; i++) {
            int idx = w * 6 + i;              // 0..47
            int r = idx / 3, ch = idx % 3;    // 16 rows x 3 chunks of 256 floats
            gload_lds16(src + (long)r * 768 + ch * 256 + lane * 4,
                        &gibuf[0][r * 772 + ch * 256]);
        }
    }
    __syncthreads();   // full drain: gi[0] + hbuf[1] visible

    for (int s = 0; s < steps; s++) {
        const int cur = s & 1;

        // ---- P1: issue gi prefetch for step s+1 into gibuf[cur^1] ----
        if (s + 1 < steps) {
            int rown = KGRU ? (d ? (63 - (s + 1)) : (s + 1)) : (s + 1);
            const float* src = gi + ((long)rown * 256 + n0) * 768;
#pragma unroll
            for (int i = 0; i < 6; i++) {
                int idx = w * 6 + i;
                int r = idx / 3, ch = idx % 3;
                gload_lds16(src + (long)r * 768 + ch * 256 + lane * 4,
                            &gibuf[cur ^ 1][r * 772 + ch * 256]);
            }
        }
        // pin: all P1 loads issue before any later vmem (exact vmcnt counting)
        asm volatile("" ::: "memory");

        const unsigned short* hrd = &hbuf[cur ^ 1][0][0];
        const float* gp = &gibuf[cur][(q * 4) * 772 + wcol + c];
        unsigned short* hwr = &hbuf[cur][q * 4][wcol + c];
        const int out_row = KGRU ? (d ? (63 - s) : s) : s;

        // ---- per-hh pass: 3-gate MFMA (12 acc regs live) + gate math ----
#pragma unroll
        for (int hh = 0; hh < 2; hh++) {
            f32x4 ar = (f32x4){0.f, 0.f, 0.f, 0.f};
            f32x4 az = (f32x4){0.f, 0.f, 0.f, 0.f};
            f32x4 an = (f32x4){0.f, 0.f, 0.f, 0.f};
#pragma unroll
            for (int kt = 0; kt < 8; kt++) {
                bf16x8 a = *(const bf16x8*)&hrd[c * 264 + kt * 32 + q8];
                ar = __builtin_amdgcn_mfma_f32_16x16x32_bf16(a, Bf[0 + hh][kt], ar, 0, 0, 0);
                az = __builtin_amdgcn_mfma_f32_16x16x32_bf16(a, Bf[2 + hh][kt], az, 0, 0, 0);
                an = __builtin_amdgcn_mfma_f32_16x16x32_bf16(a, Bf[4 + hh][kt], an, 0, 0, 0);
            }
#pragma unroll
            for (int rg = 0; rg < 4; rg++) {
                float gr = gp[rg * 772 +       hh * 16];
                float gz = gp[rg * 772 + 256 + hh * 16];
                float gn = gp[rg * 772 + 512 + hh * 16];
                float r  = __builtin_amdgcn_rcpf(1.f + __expf(-(gr + ar[rg])));
                float zg = __builtin_amdgcn_rcpf(1.f + __expf(-(gz + az[rg])));
                float nn = 1.f - 2.f * __builtin_amdgcn_rcpf(1.f + __expf(2.f * (gn + r * an[rg])));
                float hv = (1.f - zg) * nn + zg * hreg[hh][rg];
                hreg[hh][rg] = hv;
                hwr[rg * 264 + hh * 16] = f2b(hv);
                if (KGRU)
                    outp[((long)(n0 + q * 4 + rg) * 64 + out_row) * 512 + d * 256 + wcol + hh * 16 + c] = hv;
                else
                    outp[((long)s * 256 + n0 + q * 4 + rg) * 256 + wcol + hh * 16 + c] = hv;
            }
            // keep the two hh passes' LDS reads from being CSE'd into extra
            // live registers (pressure control; correctness unaffected)
            asm volatile("" ::: "memory");
        }

        // ---- P5: single counted barrier ----
        asm volatile("s_waitcnt vmcnt(8) lgkmcnt(0)" ::: "memory");
        __builtin_amdgcn_sched_barrier(0);
        __builtin_amdgcn_s_barrier();
        __builtin_amdgcn_sched_barrier(0);
    }

    if (!KGRU) {
#pragma unroll
        for (int hh = 0; hh < 2; hh++)
#pragma unroll
            for (int rg = 0; rg < 4; rg++)
                h_state[(long)(n0 + q * 4 + rg) * 256 + wcol + hh * 16 + c] = hreg[hh][rg];
    }
}

// ---------------------------------------------------------------------------
// Epilogue: per (t,n) write a, v=critic(h), h copy, softmax(logits).
// ---------------------------------------------------------------------------
__global__ __launch_bounds__(64) void epilogue_k(
    const float* __restrict__ Hallc, const float* __restrict__ Lc,
    const int* __restrict__ actions,
    const float* __restrict__ critic_W, const float* __restrict__ critic_b,
    float* __restrict__ out, int t0)
{
    int m = blockIdx.x;               // tl*256+n
    int tl = m >> 8, n = m & 255;
    int t = t0 + tl;
    int j = threadIdx.x;              // 0..63
    long o = ((long)t * 256 + n) * 322;
    const float* h = Hallc + (long)m * 256;
    float part = 0.f;
#pragma unroll
    for (int i = 0; i < 4; i++) {
        float hv = h[j + 64 * i];
        out[o + 2 + j + 64 * i] = hv;
        part += hv * critic_W[j + 64 * i];
    }
    for (int off = 32; off > 0; off >>= 1) part += __shfl_down(part, off);
    if (j == 0) {
        out[o]     = (float)actions[(long)t * 256 + n];
        out[o + 1] = part + critic_b[0];
    }
    float x = Lc[(long)m * 64 + j];
    float mx = x;
    for (int off = 32; off > 0; off >>= 1) mx = fmaxf(mx, __shfl_down(mx, off));
    mx = __shfl(mx, 0);
    float e = __expf(x - mx);
    float ssum = e;
    for (int off = 32; off > 0; off >>= 1) ssum += __shfl_down(ssum, off);
    ssum = __shfl(ssum, 0);
    out[o + 258 + j] = e / ssum;
}

// ---------------------------------------------------------------------------
extern "C" void kernel_launch(void* const* d_in, const int* in_sizes, int n_in,
                              void* d_out, int out_size, void* d_ws, size_t ws_size,
                              hipStream_t stream)
{
    const float* values   = (const float*)d_in[0];
    const float* mdp      = (const float*)d_in[1];
    const int*   actions  = (const int*)  d_in[2];
    const int*   a0       = (const int*)  d_in[3];
    const float* h0       = (const float*)d_in[4];
    const float* emb_W    = (const float*)d_in[5];
    const float* emb_b    = (const float*)d_in[6];
    const float* gfw_Wih  = (const float*)d_in[7];
    const float* gfw_Whh  = (const float*)d_in[8];
    const float* gfw_bih  = (const float*)d_in[9];
    const float* gfw_bhh  = (const float*)d_in[10];
    const float* gbw_Wih  = (const float*)d_in[11];
    const float* gbw_Whh  = (const float*)d_in[12];
    const float* gbw_bih  = (const float*)d_in[13];
    const float* gbw_bhh  = (const float*)d_in[14];
    const float* f0_W     = (const float*)d_in[15];
    const float* f0_b     = (const float*)d_in[16];
    const float* f1_W     = (const float*)d_in[17];
    const float* f1_b     = (const float*)d_in[18];
    const float* cell_Wih = (const float*)d_in[19];
    const float* cell_Whh = (const float*)d_in[20];
    const float* cell_bih = (const float*)d_in[21];
    const float* cell_bhh = (const float*)d_in[22];
    const float* critic_W = (const float*)d_in[23];
    const float* critic_b = (const float*)d_in[24];
    const float* qg_W     = (const float*)d_in[25];
    const float* qg_b     = (const float*)d_in[26];
    float* out = (float*)d_out;

    char* base = (char*)d_ws;
    size_t off = 0;
    auto alloc = [&](size_t nf) -> float* {
        float* p = (float*)(base + off);
        off += nf * sizeof(float);
        off = (off + 255) & ~(size_t)255;
        return p;
    };
    float* Mbuf   = alloc(16384ull * 256);   // (n,s,H) line embeddings
    float* Mseq   = alloc(16384ull * 256);   // (s,n,H)
    float* gfA    = alloc(16384ull * 768);   // fw gate inputs (bias folded)
    float* gbA    = alloc(16384ull * 768);   // bw gate inputs (bias folded)
    float* Kbuf   = alloc(256ull * 64 * 512);// K (n, s, 2H)
    float* PKf    = alloc(98304);            // packed Whh frags bf16: 196608 shorts = 384KB
    float* PKb    = alloc(98304);
    float* PKc    = alloc(98304);
    float* hstate = alloc(256ull * 256);
    float* Xc     = alloc(16384ull * 320);
    float* X0c    = alloc(16384ull * 256);
    float* X1c    = alloc(16384ull * 256);
    float* GIc    = alloc(16384ull * 768);
    float* Qc     = alloc(16384ull * 512);
    float* Lc     = alloc(16384ull * 64);
    float* Hallc  = alloc(16384ull * 256);
    float* bias_f = alloc(768);
    float* bias_b = alloc(768);
    float* bias_c = alloc(768);
    (void)ws_size; (void)in_sizes; (void)n_in; (void)out_size;

    dim3 blk(256);

    // Phase 1: embeddings + line-GRU gate inputs + weight prep
    gemm_f32<false, 0><<<dim3(4, 256, 1), blk, 0, stream>>>(
        mdp, 128, 0, emb_W, 256, 0, emb_b, Mbuf, 256, 0, 16384, 256, 128);
    seq_major<<<dim3(16384), blk, 0, stream>>>(Mbuf, Mseq);
    pack_w<<<dim3(96, 3, 1), blk, 0, stream>>>(
        gfw_Whh, gbw_Whh, cell_Whh,
        (unsigned short*)PKf, (unsigned short*)PKb, (unsigned short*)PKc);
    combine_bias<<<dim3(3), blk, 0, stream>>>(gfw_bih, gfw_bhh, gbw_bih, gbw_bhh,
                                              cell_bih, cell_bhh, bias_f, bias_b, bias_c);
    gemm_f32<false, 0><<<dim3(12, 256, 1), blk, 0, stream>>>(
        Mseq, 256, 0, gfw_Wih, 768, 0, bias_f, gfA, 768, 0, 16384, 768, 256);
    gemm_f32<false, 0><<<dim3(12, 256, 1), blk, 0, stream>>>(
        Mseq, 256, 0, gbw_Wih, 768, 0, bias_b, gbA, 768, 0, 16384, 768, 256);
    scan_mfma<1><<<dim3(16, 2, 1), dim3(512), 0, stream>>>(
        gfA, gbA, (const unsigned short*)PKf, (const unsigned short*)PKb,
        nullptr, Kbuf, nullptr, 64);

    // Phase 2/3: chunked x-path GEMMs -> scan -> query/logits/epilogue
    for (int c = 0; c < NCHUNK; c++) {
        int t0 = c * TCHUNK;
        build_x<<<dim3(16384), dim3(320), 0, stream>>>(values, Mbuf, actions, a0, Xc, t0);
        gemm_f32<false, 1><<<dim3(4, 256, 1), blk, 0, stream>>>(
            Xc, 320, 0, f0_W, 256, 0, f0_b, X0c, 256, 0, 16384, 256, 320);
        gemm_f32<false, 1><<<dim3(4, 256, 1), blk, 0, stream>>>(
            X0c, 256, 0, f1_W, 256, 0, f1_b, X1c, 256, 0, 16384, 256, 256);
        gemm_f32<false, 0><<<dim3(12, 256, 1), blk, 0, stream>>>(
            X1c, 256, 0, cell_Wih, 768, 0, bias_c, GIc, 768, 0, 16384, 768, 256);
        scan_mfma<0><<<dim3(16, 1, 1), dim3(512), 0, stream>>>(
            GIc, nullptr, (const unsigned short*)PKc, nullptr,
            (c == 0) ? h0 : (const float*)hstate, Hallc, hstate, TCHUNK);
        gemm_f32<false, 0><<<dim3(8, 256, 1), blk, 0, stream>>>(
            Hallc, 256, 0, qg_W, 512, 0, qg_b, Qc, 512, 0, 16384, 512, 256);
        gemm_f32<true, 0><<<dim3(1, 1, 256), blk, 0, stream>>>(
            Qc, 131072, 512, Kbuf, 512, 32768, nullptr, Lc, 16384, 64, 64, 64, 512);
        epilogue_k<<<dim3(16384), dim3(64), 0, stream>>>(
            Hallc, Lc, actions, critic_W, critic_b, out, t0);
    }
}